// Round 4
// baseline (195.108 us; speedup 1.0000x reference)
//
#include <hip/hip_runtime.h>
#include <stdint.h>

// Problem constants
#define DM 512
#define NH 8
#define HDIM 64
#define TT 4096
#define PP 1024

typedef float f32x4 __attribute__((ext_vector_type(4)));
typedef __bf16 bf16x8 __attribute__((ext_vector_type(8)));
typedef __bf16 bf16x4 __attribute__((ext_vector_type(4)));
typedef unsigned short u16x8 __attribute__((ext_vector_type(8)));
typedef unsigned short u16x4 __attribute__((ext_vector_type(4)));
typedef unsigned int u32x2 __attribute__((ext_vector_type(2)));
typedef unsigned int u32x4 __attribute__((ext_vector_type(4)));

static __device__ __forceinline__ unsigned short f2bf(float f) {
  unsigned u = __builtin_bit_cast(unsigned, f);
  u += 0x7fff + ((u >> 16) & 1);  // RNE
  return (unsigned short)(u >> 16);
}

// truncating pack (for P: bias cancels in sum(Pv)/sum(P))
static __device__ __forceinline__ unsigned packtr(float a, float b) {
  return __builtin_amdgcn_perm(__builtin_bit_cast(unsigned, b),
                               __builtin_bit_cast(unsigned, a), 0x07060302u);
}

static __device__ __forceinline__ float fexp2(float x) {
#if __has_builtin(__builtin_amdgcn_exp2f)
  return __builtin_amdgcn_exp2f(x);
#else
  return __expf(x * 0.69314718055994531f);
#endif
}

static __device__ __forceinline__ void load_lds16(const void* g, void* l) {
  __builtin_amdgcn_global_load_lds(
      (__attribute__((address_space(1))) void*)g,
      (__attribute__((address_space(3))) void*)l, 16, 0, 0);
}

static __device__ __forceinline__ f32x4 mfma16(bf16x8 a, bf16x8 b, f32x4 c) {
  return __builtin_amdgcn_mfma_f32_16x16x32_bf16(a, b, c, 0, 0, 0);
}

// In-register P redistribution (replaces the P LDS round-trip).
static __device__ __forceinline__ bf16x8 p_exchange(unsigned w0, unsigned w1,
                                                    unsigned w2, unsigned w3,
                                                    int q, int c) {
#if __has_builtin(__builtin_amdgcn_permlane32_swap) && \
    __has_builtin(__builtin_amdgcn_permlane16_swap)
  (void)q; (void)c;
  auto s02 = __builtin_amdgcn_permlane32_swap(w0, w2, false, false);
  auto t02 = __builtin_amdgcn_permlane16_swap(s02[0], s02[1], false, false);
  auto s13 = __builtin_amdgcn_permlane32_swap(w1, w3, false, false);
  auto t13 = __builtin_amdgcn_permlane16_swap(s13[0], s13[1], false, false);
  u32x4 pd = {(unsigned)t02[0], (unsigned)t13[0], (unsigned)t02[1], (unsigned)t13[1]};
  return __builtin_bit_cast(bf16x8, pd);
#else
  const int a0 = (c + (q & 1) * 32) * 4;
  const int a2 = (c + 16 + (q & 1) * 32) * 4;
  const bool lo = (q < 2);
  unsigned d0 = lo ? (unsigned)__builtin_amdgcn_ds_bpermute(a0, (int)w0)
                   : (unsigned)__builtin_amdgcn_ds_bpermute(a0, (int)w2);
  unsigned d1 = lo ? (unsigned)__builtin_amdgcn_ds_bpermute(a0, (int)w1)
                   : (unsigned)__builtin_amdgcn_ds_bpermute(a0, (int)w3);
  unsigned d2 = lo ? (unsigned)__builtin_amdgcn_ds_bpermute(a2, (int)w0)
                   : (unsigned)__builtin_amdgcn_ds_bpermute(a2, (int)w2);
  unsigned d3 = lo ? (unsigned)__builtin_amdgcn_ds_bpermute(a2, (int)w1)
                   : (unsigned)__builtin_amdgcn_ds_bpermute(a2, (int)w3);
  u32x4 pd = {d0, d1, d2, d3};
  return __builtin_bit_cast(bf16x8, pd);
#endif
}

// ---------------------------------------------------------------------------
// Weights only: fp32 -> Wt[n][k] bf16 (transposed). 1024 blocks. Activations
// are no longer pre-converted: qkv reads fp32 directly (saves the 60 MB
// XTOK/XPAT round-trip and ~10 us of the old conv kernel).
// ---------------------------------------------------------------------------
__global__ __launch_bounds__(256) void k_convW(
    const float* __restrict__ wq, const float* __restrict__ wk,
    const float* __restrict__ wv, const float* __restrict__ wo,
    unsigned short* __restrict__ wt) {
  const int wi = blockIdx.x * 256 + threadIdx.x;  // [0, 262144)
  int wid = wi >> 16;         // 0..3 -> q,k,v,o
  int e = (wi & 65535) << 2;  // element index k*512+n
  int k = e >> 9, n = e & 511;
  const float* w = (wid == 0) ? wq : (wid == 1) ? wk : (wid == 2) ? wv : wo;
  f32x4 v = *(const f32x4*)&w[e];
  unsigned short* wtb = wt + (wid << 18);
#pragma unroll
  for (int i = 0; i < 4; ++i) wtb[(n + i) * 512 + k] = f2bf(v[i]);
}

// ---------------------------------------------------------------------------
// QKV projection GEMM, 128x128 tile. A is fp32, reg-staged (T14 split:
// issue distance-2 -> counted vmcnt -> cvt_pk_bf16 -> ds_write_b128);
// B (weights, bf16) stays on the pure-DMA 3-buffer counted-vmcnt path.
// Per wave per stage: 4 A-loads (f32x4) + 2 B-DMAs = 6 vm ops; steady-state
// vmcnt(6) retires stage i+1's ops, leaving stage i+2's 6 in flight.
// MODE 0/1: operand-swapped mfma -> u16x4 packed stores.
// MODE 2: unswapped, u16x4 packed transposed stores (VT layout).
// ---------------------------------------------------------------------------
template <int MODE>
__device__ __forceinline__ void gemm_qkv_body(
    const float* __restrict__ A, const unsigned short* __restrict__ Wt,
    const float* __restrict__ bias, unsigned short* __restrict__ outb,
    int bid, unsigned short* sA, unsigned short* sB, float scale) {
  const int tid = threadIdx.x;
  const int wave = tid >> 6, lane = tid & 63;
  const int q = lane >> 4, c = lane & 15;
  const int bm = bid >> 2, bn = bid & 3;
  const int wm = (wave >> 1) * 64, wn = (wave & 1) * 64;
  const int lr = lane >> 2, lc = (lane & 3) * 8;

  f32x4 acc[4][4];
#pragma unroll
  for (int i = 0; i < 4; ++i)
#pragma unroll
    for (int j = 0; j < 4; ++j) acc[i][j] = (f32x4){0.f, 0.f, 0.f, 0.f};

  const int rowA0 = bm * 128, rowB0 = bn * 128;

  f32x4 rA0[2][2], rA1[2][2];  // two named in-flight sets (stage t -> set t&1)

  // issue 4 fp32 loads for stage t into r (distance-2 prefetch)
  auto a_issue = [&](int t, f32x4 (&r)[2][2]) {
    const int kn = t * 32;
#pragma unroll
    for (int qq = 0; qq < 2; ++qq) {
      const float* src = &A[(rowA0 + (wave * 2 + qq) * 16 + lr) * 512 + kn + lc];
      r[qq][0] = *(const f32x4*)src;
      r[qq][1] = *(const f32x4*)(src + 4);
    }
  };
  // convert stage t's fp32 regs -> bf16 -> LDS buf (t&1); same linear layout
  // as the old DMA path (chunk*512 + lr*32 + lc), so fragment reads unchanged
  auto a_write = [&](int t, f32x4 (&r)[2][2]) {
    unsigned short* dA = sA + (t & 1) * 4096;
#pragma unroll
    for (int qq = 0; qq < 2; ++qq) {
      u16x4 lo = __builtin_bit_cast(u16x4, __builtin_convertvector(r[qq][0], bf16x4));
      u16x4 hi = __builtin_bit_cast(u16x4, __builtin_convertvector(r[qq][1], bf16x4));
      u16x8 o = {lo[0], lo[1], lo[2], lo[3], hi[0], hi[1], hi[2], hi[3]};
      *(u16x8*)&dA[(wave * 2 + qq) * 512 + lr * 32 + lc] = o;
    }
  };
  // weights: DMA stage t into sB buf t%3
  auto b_issue = [&](int t) {
    const int kn = t * 32;
    unsigned short* dB = sB + (t % 3) * 4096;
#pragma unroll
    for (int qq = 0; qq < 2; ++qq) {
      const int chunk = wave * 2 + qq;
      load_lds16(&Wt[(rowB0 + chunk * 16 + lr) * 512 + kn + lc], &dB[chunk * 512]);
    }
  };

  // prologue: A(0),B(0),A(1),B(1) in flight (12 vm ops); retire A(0)+B(0)
  a_issue(0, rA0);
  b_issue(0);
  a_issue(1, rA1);
  b_issue(1);
  asm volatile("s_waitcnt vmcnt(6)" ::: "memory");
  a_write(0, rA0);
  asm volatile("s_waitcnt lgkmcnt(0)" ::: "memory");
  __builtin_amdgcn_s_barrier();

#pragma unroll 1
  for (int i = 0; i < 16; ++i) {
    const bool ev = ((i & 1) == 0);
    if (i + 2 < 16) {
      if (ev) a_issue(i + 2, rA0);  // (i+2) even -> set 0
      else    a_issue(i + 2, rA1);
      b_issue(i + 2);
    }
    const unsigned short* curA = sA + (i & 1) * 4096;
    const unsigned short* curB = sB + (i % 3) * 4096;
    bf16x8 af[4], bfr[4];
#pragma unroll
    for (int mt = 0; mt < 4; ++mt)
      af[mt] = __builtin_bit_cast(bf16x8, *(const u16x8*)&curA[(wm + mt * 16 + c) * 32 + q * 8]);
#pragma unroll
    for (int nt = 0; nt < 4; ++nt)
      bfr[nt] = __builtin_bit_cast(bf16x8, *(const u16x8*)&curB[(wn + nt * 16 + c) * 32 + q * 8]);
#pragma unroll
    for (int mt = 0; mt < 4; ++mt)
#pragma unroll
      for (int nt = 0; nt < 4; ++nt) {
        if (MODE == 2)
          acc[mt][nt] = mfma16(af[mt], bfr[nt], acc[mt][nt]);
        else  // swapped: fragment is C^T -> cols in regs
          acc[mt][nt] = mfma16(bfr[nt], af[mt], acc[mt][nt]);
      }
    if (i < 15) {
      // retire stage i+1's 6 ops; keep stage i+2's 6 in flight (i<14)
      if (i < 14) asm volatile("s_waitcnt vmcnt(6)" ::: "memory");
      else        asm volatile("s_waitcnt vmcnt(0)" ::: "memory");
      if (ev) a_write(i + 1, rA1);  // (i+1) odd -> set 1
      else    a_write(i + 1, rA0);
      asm volatile("s_waitcnt lgkmcnt(0)" ::: "memory");
      __builtin_amdgcn_s_barrier();
    }
  }

  if (MODE == 2) {
    // unswapped: row = ...+q*4+r (consecutive), col = ...+c
#pragma unroll
    for (int nt = 0; nt < 4; ++nt) {
      const int col = bn * 128 + wn + nt * 16 + c;
      const float bcol = bias[col];
#pragma unroll
      for (int mt = 0; mt < 4; ++mt) {
        const int row0 = bm * 128 + wm + mt * 16 + q * 4;
        u16x4 o;
#pragma unroll
        for (int r = 0; r < 4; ++r) o[r] = f2bf(acc[mt][nt][r] + bcol);
        // VT[b][col][p]: 4 consecutive p per store, same b (row0 % 4 == 0)
        *(u16x4*)&outb[((row0 >> 10) << 19) + (col << 10) + (row0 & 1023)] = o;
      }
    }
  } else {
    // swapped: row = ...+c, col = ...+q*4+r (consecutive)
#pragma unroll
    for (int mt = 0; mt < 4; ++mt) {
      const int row = bm * 128 + wm + mt * 16 + c;
#pragma unroll
      for (int nt = 0; nt < 4; ++nt) {
        const int col0 = bn * 128 + wn + nt * 16 + q * 4;
        const f32x4 bv = *(const f32x4*)&bias[col0];
        u16x4 o;
#pragma unroll
        for (int r = 0; r < 4; ++r) o[r] = f2bf((acc[mt][nt][r] + bv[r]) * scale);
        *(u16x4*)&outb[row * 512 + col0] = o;
      }
    }
  }
}

__global__ __launch_bounds__(256, 3) void k_gemm_qkv(
    const float* __restrict__ tok, const float* __restrict__ pat,
    const unsigned short* __restrict__ WT,
    const float* __restrict__ bq, const float* __restrict__ bk,
    const float* __restrict__ bv,
    unsigned short* __restrict__ QB, unsigned short* __restrict__ KB,
    unsigned short* __restrict__ VTB) {
  __shared__ unsigned short sA[2 * 128 * 32];
  __shared__ unsigned short sB[3 * 128 * 32];
  const int bid = blockIdx.x;
  if (bid < 512) {
    // scale = 0.125 * log2(e): scores come out in log2 domain for exp2
    gemm_qkv_body<0>(tok, WT, bq, QB, bid, sA, sB, 0.18033688011112042f);
  } else if (bid < 640) {
    gemm_qkv_body<1>(pat, WT + 262144, bk, KB, bid - 512, sA, sB, 1.0f);
  } else {
    gemm_qkv_body<2>(pat, WT + 524288, bv, VTB, bid - 640, sA, sB, 1.0f);
  }
}

// ---------------------------------------------------------------------------
// Out-projection GEMM, 128x128, 3-buffer counted-vmcnt DMA pipeline:
// out = CTX @ Wo + bo + resid (fp32), pure f32x4 epilogue. (Unchanged.)
// ---------------------------------------------------------------------------
__global__ __launch_bounds__(256) void k_gemm_o(
    const unsigned short* __restrict__ A, const unsigned short* __restrict__ Wt,
    const float* __restrict__ bias, float* __restrict__ outf,
    const float* __restrict__ resid) {
  __shared__ unsigned short sA[3 * 128 * 32];
  __shared__ unsigned short sB[3 * 128 * 32];
  const int tid = threadIdx.x;
  const int wave = tid >> 6, lane = tid & 63;
  const int q = lane >> 4, c = lane & 15;
  const int bm = blockIdx.x >> 2, bn = blockIdx.x & 3;
  const int wm = (wave >> 1) * 64, wn = (wave & 1) * 64;
  const int lr = lane >> 2, lc = (lane & 3) * 8;

  f32x4 acc[4][4];
#pragma unroll
  for (int i = 0; i < 4; ++i)
#pragma unroll
    for (int j = 0; j < 4; ++j) acc[i][j] = (f32x4){0.f, 0.f, 0.f, 0.f};

  const int rowA0 = bm * 128, rowB0 = bn * 128;

  auto stage = [&](int t) {
    const int kn = t * 32;
    unsigned short* dA = sA + (t % 3) * 4096;
    unsigned short* dB = sB + (t % 3) * 4096;
#pragma unroll
    for (int qq = 0; qq < 2; ++qq) {
      const int chunk = wave * 2 + qq;
      load_lds16(&A[(rowA0 + chunk * 16 + lr) * 512 + kn + lc], &dA[chunk * 512]);
      load_lds16(&Wt[(rowB0 + chunk * 16 + lr) * 512 + kn + lc], &dB[chunk * 512]);
    }
  };

  stage(0);
  stage(1);
  asm volatile("s_waitcnt vmcnt(4)" ::: "memory");
  __builtin_amdgcn_s_barrier();

#pragma unroll 1
  for (int i = 0; i < 16; ++i) {
    if (i + 2 < 16) stage(i + 2);
    const unsigned short* curA = sA + (i % 3) * 4096;
    const unsigned short* curB = sB + (i % 3) * 4096;
    bf16x8 af[4], bfr[4];
#pragma unroll
    for (int mt = 0; mt < 4; ++mt)
      af[mt] = __builtin_bit_cast(bf16x8, *(const u16x8*)&curA[(wm + mt * 16 + c) * 32 + q * 8]);
#pragma unroll
    for (int nt = 0; nt < 4; ++nt)
      bfr[nt] = __builtin_bit_cast(bf16x8, *(const u16x8*)&curB[(wn + nt * 16 + c) * 32 + q * 8]);
#pragma unroll
    for (int mt = 0; mt < 4; ++mt)
#pragma unroll
      for (int nt = 0; nt < 4; ++nt)
        acc[mt][nt] = mfma16(bfr[nt], af[mt], acc[mt][nt]);  // swapped: C^T frag
    if (i < 15) {
      if (i + 2 < 16) asm volatile("s_waitcnt vmcnt(4)" ::: "memory");
      else            asm volatile("s_waitcnt vmcnt(0)" ::: "memory");
      __builtin_amdgcn_s_barrier();
    }
  }

#pragma unroll
  for (int mt = 0; mt < 4; ++mt) {
    const int row = bm * 128 + wm + mt * 16 + c;
#pragma unroll
    for (int nt = 0; nt < 4; ++nt) {
      const int col0 = bn * 128 + wn + nt * 16 + q * 4;
      const int o = row * 512 + col0;
      const f32x4 bv = *(const f32x4*)&bias[col0];
      const f32x4 rv = *(const f32x4*)&resid[o];
      f32x4 ov;
#pragma unroll
      for (int r = 0; r < 4; ++r) ov[r] = acc[mt][nt][r] + bv[r] + rv[r];
      *(f32x4*)&outf[o] = ov;
    }
  }
}

// ---------------------------------------------------------------------------
// Kernel 3: block-causal cross attention, no-max softmax in log2 domain.
// P redistribution fully in-register (permlane16/32_swap network). (Unchanged.)
// ---------------------------------------------------------------------------
__global__ __launch_bounds__(256) void k_attn(
    const unsigned short* __restrict__ Q,   // [B*T][512], scaled by .125*log2e
    const unsigned short* __restrict__ K,   // [B*P][512]
    const unsigned short* __restrict__ VT,  // [B][512][1024]
    unsigned short* __restrict__ CTX) {     // [B*T][512]
  __shared__ unsigned short sK[2][32 * 88];
  __shared__ unsigned short sV[2][64 * 40];

  const int tid = threadIdx.x;
  const int lane = tid & 63;
  const int wave = tid >> 6;
  const int q = lane >> 4, c = lane & 15;

  const int g = blockIdx.x >> 5;               // [0,32)
  const int tg = (g < 16) ? g : 47 - g;        // uniform-per-CU mapping
  const int bh = blockIdx.x & 31;
  const int b = bh >> 3, h = bh & 7;
  const int t0 = tg * 128 + wave * 32;
  const int tA = t0 + c, tB = t0 + 16 + c;

  const int qbA = (b * TT + tA) * 512 + h * 64 + q * 8;
  const int qbB = (b * TT + tB) * 512 + h * 64 + q * 8;
  const bf16x8 qfA0 = __builtin_bit_cast(bf16x8, *(const u16x8*)&Q[qbA]);
  const bf16x8 qfA1 = __builtin_bit_cast(bf16x8, *(const u16x8*)&Q[qbA + 32]);
  const bf16x8 qfB0 = __builtin_bit_cast(bf16x8, *(const u16x8*)&Q[qbB]);
  const bf16x8 qfB1 = __builtin_bit_cast(bf16x8, *(const u16x8*)&Q[qbB + 32]);

  f32x4 oA[4], oB[4];
#pragma unroll
  for (int m = 0; m < 4; ++m) {
    oA[m] = (f32x4){0.f, 0.f, 0.f, 0.f};
    oB[m] = (f32x4){0.f, 0.f, 0.f, 0.f};
  }
  f32x4 lA = (f32x4){0.f, 0.f, 0.f, 0.f};
  f32x4 lB = lA;
  const u16x8 onesu = {0x3F80, 0x3F80, 0x3F80, 0x3F80, 0x3F80, 0x3F80, 0x3F80, 0x3F80};
  const bf16x8 ones = __builtin_bit_cast(bf16x8, onesu);

  const int ntile = tg + 1;
  const int krow = tid >> 3, kcol = (tid & 7) * 8;
  const int vrow = tid >> 2, vcol = (tid & 3) * 8;
  const int kg = (b * PP + krow) * 512 + h * 64 + kcol;
  const int vg = (b << 19) + ((h * 64 + vrow) << 10) + vcol;

  // stage tile 0
  u16x8 kreg = *(const u16x8*)&K[kg];
  u16x8 vreg = *(const u16x8*)&VT[vg];
  *(u16x8*)&sK[0][krow * 88 + kcol] = kreg;
  *(u16x8*)&sV[0][vrow * 40 + vcol] = vreg;
  __syncthreads();

#pragma unroll 1
  for (int pt = 0; pt < ntile; ++pt) {
    const int buf = pt & 1;
    const bool more = (pt + 1 < ntile);
    if (more) {  // prefetch next tile (overlaps this tile's compute)
      kreg = *(const u16x8*)&K[kg + (pt + 1) * 32 * 512];
      vreg = *(const u16x8*)&VT[vg + (pt + 1) * 32];
    }
    const unsigned short* bK = sK[buf];
    const unsigned short* bV = sV[buf];

    const bf16x8 ka0 = __builtin_bit_cast(bf16x8, *(const u16x8*)&bK[c * 88 + q * 8]);
    const bf16x8 ka1 = __builtin_bit_cast(bf16x8, *(const u16x8*)&bK[c * 88 + 32 + q * 8]);
    const bf16x8 kb0 = __builtin_bit_cast(bf16x8, *(const u16x8*)&bK[(16 + c) * 88 + q * 8]);
    const bf16x8 kb1 = __builtin_bit_cast(bf16x8, *(const u16x8*)&bK[(16 + c) * 88 + 32 + q * 8]);

    const f32x4 z = (f32x4){0.f, 0.f, 0.f, 0.f};
    __builtin_amdgcn_s_setprio(1);
    f32x4 sA0 = mfma16(ka1, qfA1, mfma16(ka0, qfA0, z));  // patches p0+q*4+r
    f32x4 sA1 = mfma16(kb1, qfA1, mfma16(kb0, qfA0, z));  // patches p0+16+q*4+r
    f32x4 sB0 = mfma16(ka1, qfB1, mfma16(ka0, qfB0, z));
    f32x4 sB1 = mfma16(kb1, qfB1, mfma16(kb0, qfB0, z));
    __builtin_amdgcn_s_setprio(0);

    if (pt + 1 == ntile) {  // only the last tile crosses the causal boundary
      const int p0 = pt * 32;
      const int limA = tA >> 2, limB = tB >> 2;
      const int pb0 = p0 + q * 4, pb1 = p0 + 16 + q * 4;
#pragma unroll
      for (int r = 0; r < 4; ++r) {
        if (pb0 + r > limA) sA0[r] = -1e30f;
        if (pb1 + r > limA) sA1[r] = -1e30f;
        if (pb0 + r > limB) sB0[r] = -1e30f;
        if (pb1 + r > limB) sB1[r] = -1e30f;
      }
    }

    float pA0[4], pA1[4], pB0[4], pB1[4];
#pragma unroll
    for (int r = 0; r < 4; ++r) {
      pA0[r] = fexp2(sA0[r]);
      pA1[r] = fexp2(sA1[r]);
      pB0[r] = fexp2(sB0[r]);
      pB1[r] = fexp2(sB1[r]);
    }

    // pack + in-register exchange (no LDS)
    const bf16x8 pbA = p_exchange(packtr(pA0[0], pA0[1]), packtr(pA0[2], pA0[3]),
                                  packtr(pA1[0], pA1[1]), packtr(pA1[2], pA1[3]), q, c);
    const bf16x8 pbB = p_exchange(packtr(pB0[0], pB0[1]), packtr(pB0[2], pB0[3]),
                                  packtr(pB1[0], pB1[1]), packtr(pB1[2], pB1[3]), q, c);

    // ctx^T += V^T . P^T ; l += ones . P^T
    __builtin_amdgcn_s_setprio(1);
#pragma unroll
    for (int mt = 0; mt < 4; ++mt) {
      const bf16x8 vf =
          __builtin_bit_cast(bf16x8, *(const u16x8*)&bV[(mt * 16 + c) * 40 + q * 8]);
      oA[mt] = mfma16(vf, pbA, oA[mt]);
      oB[mt] = mfma16(vf, pbB, oB[mt]);
    }
    lA = mfma16(ones, pbA, lA);
    lB = mfma16(ones, pbB, lB);
    __builtin_amdgcn_s_setprio(0);

    if (more) {  // write next tile into the other buffer, single barrier
      *(u16x8*)&sK[buf ^ 1][krow * 88 + kcol] = kreg;
      *(u16x8*)&sV[buf ^ 1][vrow * 40 + vcol] = vreg;
      __syncthreads();
    }
  }

  const float invA = 1.f / lA[0];
  const float invB = 1.f / lB[0];
  const int obA = (b * TT + tA) * 512 + h * 64 + q * 4;
  const int obB = (b * TT + tB) * 512 + h * 64 + q * 4;
#pragma unroll
  for (int mt = 0; mt < 4; ++mt) {
    u16x4 oa, ob;
#pragma unroll
    for (int r = 0; r < 4; ++r) {
      oa[r] = f2bf(oA[mt][r] * invA);
      ob[r] = f2bf(oB[mt][r] * invB);
    }
    *(u16x4*)&CTX[obA + mt * 16] = oa;
    *(u16x4*)&CTX[obB + mt * 16] = ob;
  }
}

// ---------------------------------------------------------------------------
extern "C" void kernel_launch(void* const* d_in, const int* in_sizes, int n_in,
                              void* d_out, int out_size, void* d_ws, size_t ws_size,
                              hipStream_t stream) {
  const float* tok = (const float*)d_in[0];
  const float* pat = (const float*)d_in[1];
  const float* Wq = (const float*)d_in[2];
  const float* Wk = (const float*)d_in[3];
  const float* Wv = (const float*)d_in[4];
  const float* bq = (const float*)d_in[5];
  const float* bk = (const float*)d_in[6];
  const float* bv = (const float*)d_in[7];
  const float* Wo = (const float*)d_in[8];
  const float* bo = (const float*)d_in[9];
  float* out = (float*)d_out;

  unsigned short* ws = (unsigned short*)d_ws;
  unsigned short* WT = ws;                   // 4 x 512 x 512
  unsigned short* QB = ws + 11534336;        // 16384 x 512
  unsigned short* KB = ws + 19922944;        // 4096 x 512
  unsigned short* VTB = ws + 22020096;       // [4][512][1024]
  unsigned short* CTX = ws + 24117248;       // 16384 x 512   (ends 65 MB)

  k_convW<<<1024, 256, 0, stream>>>(Wq, Wk, Wv, Wo, WT);
  k_gemm_qkv<<<768, 256, 0, stream>>>(tok, pat, WT, bq, bk, bv, QB, KB, VTB);
  k_attn<<<1024, 256, 0, stream>>>(QB, KB, VTB, CTX);
  k_gemm_o<<<512, 256, 0, stream>>>(CTX, WT + 786432, bo, out, tok);
}

// Round 5
// 191.991 us; speedup vs baseline: 1.0162x; 1.0162x over previous
//
#include <hip/hip_runtime.h>
#include <stdint.h>

// Problem constants
#define DM 512
#define NH 8
#define HDIM 64
#define TT 4096
#define PP 1024

typedef float f32x4 __attribute__((ext_vector_type(4)));
typedef __bf16 bf16x8 __attribute__((ext_vector_type(8)));
typedef __bf16 bf16x4 __attribute__((ext_vector_type(4)));
typedef unsigned short u16x8 __attribute__((ext_vector_type(8)));
typedef unsigned short u16x4 __attribute__((ext_vector_type(4)));
typedef unsigned int u32x2 __attribute__((ext_vector_type(2)));
typedef unsigned int u32x4 __attribute__((ext_vector_type(4)));

static __device__ __forceinline__ unsigned short f2bf(float f) {
  unsigned u = __builtin_bit_cast(unsigned, f);
  u += 0x7fff + ((u >> 16) & 1);  // RNE
  return (unsigned short)(u >> 16);
}

// truncating pack (for P: bias cancels in sum(Pv)/sum(P))
static __device__ __forceinline__ unsigned packtr(float a, float b) {
  return __builtin_amdgcn_perm(__builtin_bit_cast(unsigned, b),
                               __builtin_bit_cast(unsigned, a), 0x07060302u);
}

static __device__ __forceinline__ float fexp2(float x) {
#if __has_builtin(__builtin_amdgcn_exp2f)
  return __builtin_amdgcn_exp2f(x);
#else
  return __expf(x * 0.69314718055994531f);
#endif
}

static __device__ __forceinline__ void load_lds16(const void* g, void* l) {
  __builtin_amdgcn_global_load_lds(
      (__attribute__((address_space(1))) void*)g,
      (__attribute__((address_space(3))) void*)l, 16, 0, 0);
}

static __device__ __forceinline__ f32x4 mfma16(bf16x8 a, bf16x8 b, f32x4 c) {
  return __builtin_amdgcn_mfma_f32_16x16x32_bf16(a, b, c, 0, 0, 0);
}

// In-register P redistribution (replaces the P LDS round-trip).
static __device__ __forceinline__ bf16x8 p_exchange(unsigned w0, unsigned w1,
                                                    unsigned w2, unsigned w3,
                                                    int q, int c) {
#if __has_builtin(__builtin_amdgcn_permlane32_swap) && \
    __has_builtin(__builtin_amdgcn_permlane16_swap)
  (void)q; (void)c;
  auto s02 = __builtin_amdgcn_permlane32_swap(w0, w2, false, false);
  auto t02 = __builtin_amdgcn_permlane16_swap(s02[0], s02[1], false, false);
  auto s13 = __builtin_amdgcn_permlane32_swap(w1, w3, false, false);
  auto t13 = __builtin_amdgcn_permlane16_swap(s13[0], s13[1], false, false);
  u32x4 pd = {(unsigned)t02[0], (unsigned)t13[0], (unsigned)t02[1], (unsigned)t13[1]};
  return __builtin_bit_cast(bf16x8, pd);
#else
  const int a0 = (c + (q & 1) * 32) * 4;
  const int a2 = (c + 16 + (q & 1) * 32) * 4;
  const bool lo = (q < 2);
  unsigned d0 = lo ? (unsigned)__builtin_amdgcn_ds_bpermute(a0, (int)w0)
                   : (unsigned)__builtin_amdgcn_ds_bpermute(a0, (int)w2);
  unsigned d1 = lo ? (unsigned)__builtin_amdgcn_ds_bpermute(a0, (int)w1)
                   : (unsigned)__builtin_amdgcn_ds_bpermute(a0, (int)w3);
  unsigned d2 = lo ? (unsigned)__builtin_amdgcn_ds_bpermute(a2, (int)w0)
                   : (unsigned)__builtin_amdgcn_ds_bpermute(a2, (int)w2);
  unsigned d3 = lo ? (unsigned)__builtin_amdgcn_ds_bpermute(a2, (int)w1)
                   : (unsigned)__builtin_amdgcn_ds_bpermute(a2, (int)w3);
  u32x4 pd = {d0, d1, d2, d3};
  return __builtin_bit_cast(bf16x8, pd);
#endif
}

// ---------------------------------------------------------------------------
// LDS bank swizzle for the 128x32 bf16 GEMM tiles (64B rows, 4 x 16B slots).
// Layout rule: LDS slot (row, s) stores global 16B-group g = (s - (row>>1)) & 3.
//  - fragment READ of colgroup q at in-chunk row c  -> slot (q + (c>>1)) & 3
//  - reg-staged WRITE (thread owns colgroup lane&3 at row lane>>2)
//       -> slot ((lane&3) + (lane>>3)) & 3
//  - DMA source pre-swizzle (lane lands at slot lane&3, row lane>>2)
//       -> load global colgroup ((lane&3) - (lane>>3)) & 3
// Breaks the 4-way bank conflict of the naive q*8 fragment read (each 8-lane
// group previously hit only 8 of 32 banks; now all 8 bank-quads distinct).
// ---------------------------------------------------------------------------
static __device__ __forceinline__ int sw_rd(int c, int q) {
  return ((q + (c >> 1)) & 3) * 8;
}

// ---------------------------------------------------------------------------
// Weights only: fp32 -> Wt[n][k] bf16 (transposed). 1024 blocks.
// ---------------------------------------------------------------------------
__global__ __launch_bounds__(256) void k_convW(
    const float* __restrict__ wq, const float* __restrict__ wk,
    const float* __restrict__ wv, const float* __restrict__ wo,
    unsigned short* __restrict__ wt) {
  const int wi = blockIdx.x * 256 + threadIdx.x;  // [0, 262144)
  int wid = wi >> 16;         // 0..3 -> q,k,v,o
  int e = (wi & 65535) << 2;  // element index k*512+n
  int k = e >> 9, n = e & 511;
  const float* w = (wid == 0) ? wq : (wid == 1) ? wk : (wid == 2) ? wv : wo;
  f32x4 v = *(const f32x4*)&w[e];
  unsigned short* wtb = wt + (wid << 18);
#pragma unroll
  for (int i = 0; i < 4; ++i) wtb[(n + i) * 512 + k] = f2bf(v[i]);
}

// ---------------------------------------------------------------------------
// QKV projection GEMM, 128x128 tile. A fp32 reg-staged (swizzled ds_write);
// B bf16 via global_load_lds with pre-swizzled source. Counted vmcnt.
// ---------------------------------------------------------------------------
template <int MODE>
__device__ __forceinline__ void gemm_qkv_body(
    const float* __restrict__ A, const unsigned short* __restrict__ Wt,
    const float* __restrict__ bias, unsigned short* __restrict__ outb,
    int bid, unsigned short* sA, unsigned short* sB, float scale) {
  const int tid = threadIdx.x;
  const int wave = tid >> 6, lane = tid & 63;
  const int q = lane >> 4, c = lane & 15;
  const int bm = bid >> 2, bn = bid & 3;
  const int wm = (wave >> 1) * 64, wn = (wave & 1) * 64;
  const int lr = lane >> 2, lc = (lane & 3) * 8;
  const int swW = (((lane & 3) + (lane >> 3)) & 3) * 8;  // reg-staged write slot
  const int swS = (((lane & 3) - (lane >> 3)) & 3) * 8;  // DMA source group

  f32x4 acc[4][4];
#pragma unroll
  for (int i = 0; i < 4; ++i)
#pragma unroll
    for (int j = 0; j < 4; ++j) acc[i][j] = (f32x4){0.f, 0.f, 0.f, 0.f};

  const int rowA0 = bm * 128, rowB0 = bn * 128;

  f32x4 rA0[2][2], rA1[2][2];  // two named in-flight sets (stage t -> set t&1)

  // issue 4 fp32 loads for stage t (distance-2 prefetch); coalesced, unswizzled
  auto a_issue = [&](int t, f32x4 (&r)[2][2]) {
    const int kn = t * 32;
#pragma unroll
    for (int qq = 0; qq < 2; ++qq) {
      const float* src = &A[(rowA0 + (wave * 2 + qq) * 16 + lr) * 512 + kn + lc];
      r[qq][0] = *(const f32x4*)src;
      r[qq][1] = *(const f32x4*)(src + 4);
    }
  };
  // fp32 regs -> bf16 -> swizzled LDS slot
  auto a_write = [&](int t, f32x4 (&r)[2][2]) {
    unsigned short* dA = sA + (t & 1) * 4096;
#pragma unroll
    for (int qq = 0; qq < 2; ++qq) {
      u16x4 lo = __builtin_bit_cast(u16x4, __builtin_convertvector(r[qq][0], bf16x4));
      u16x4 hi = __builtin_bit_cast(u16x4, __builtin_convertvector(r[qq][1], bf16x4));
      u16x8 o = {lo[0], lo[1], lo[2], lo[3], hi[0], hi[1], hi[2], hi[3]};
      *(u16x8*)&dA[(wave * 2 + qq) * 512 + lr * 32 + swW] = o;
    }
  };
  // weights: DMA stage t into sB buf t%3 (LDS dest linear, source pre-swizzled)
  auto b_issue = [&](int t) {
    const int kn = t * 32;
    unsigned short* dB = sB + (t % 3) * 4096;
#pragma unroll
    for (int qq = 0; qq < 2; ++qq) {
      const int chunk = wave * 2 + qq;
      load_lds16(&Wt[(rowB0 + chunk * 16 + lr) * 512 + kn + swS], &dB[chunk * 512]);
    }
  };

  // prologue: A(0),B(0),A(1),B(1) in flight (12 vm ops); retire A(0)+B(0)
  a_issue(0, rA0);
  b_issue(0);
  a_issue(1, rA1);
  b_issue(1);
  asm volatile("s_waitcnt vmcnt(6)" ::: "memory");
  a_write(0, rA0);
  asm volatile("s_waitcnt lgkmcnt(0)" ::: "memory");
  __builtin_amdgcn_s_barrier();

#pragma unroll 1
  for (int i = 0; i < 16; ++i) {
    const bool ev = ((i & 1) == 0);
    if (i + 2 < 16) {
      if (ev) a_issue(i + 2, rA0);  // (i+2) even -> set 0
      else    a_issue(i + 2, rA1);
      b_issue(i + 2);
    }
    const unsigned short* curA = sA + (i & 1) * 4096;
    const unsigned short* curB = sB + (i % 3) * 4096;
    bf16x8 af[4], bfr[4];
#pragma unroll
    for (int mt = 0; mt < 4; ++mt)
      af[mt] = __builtin_bit_cast(bf16x8,
          *(const u16x8*)&curA[(wm + mt * 16 + c) * 32 + sw_rd(c, q)]);
#pragma unroll
    for (int nt = 0; nt < 4; ++nt)
      bfr[nt] = __builtin_bit_cast(bf16x8,
          *(const u16x8*)&curB[(wn + nt * 16 + c) * 32 + sw_rd(c, q)]);
#pragma unroll
    for (int mt = 0; mt < 4; ++mt)
#pragma unroll
      for (int nt = 0; nt < 4; ++nt) {
        if (MODE == 2)
          acc[mt][nt] = mfma16(af[mt], bfr[nt], acc[mt][nt]);
        else  // swapped: fragment is C^T -> cols in regs
          acc[mt][nt] = mfma16(bfr[nt], af[mt], acc[mt][nt]);
      }
    if (i < 15) {
      // retire stage i+1's 6 ops; keep stage i+2's 6 in flight (i<14)
      if (i < 14) asm volatile("s_waitcnt vmcnt(6)" ::: "memory");
      else        asm volatile("s_waitcnt vmcnt(0)" ::: "memory");
      if (ev) a_write(i + 1, rA1);  // (i+1) odd -> set 1
      else    a_write(i + 1, rA0);
      asm volatile("s_waitcnt lgkmcnt(0)" ::: "memory");
      __builtin_amdgcn_s_barrier();
    }
  }

  if (MODE == 2) {
    // unswapped: row = ...+q*4+r (consecutive), col = ...+c
#pragma unroll
    for (int nt = 0; nt < 4; ++nt) {
      const int col = bn * 128 + wn + nt * 16 + c;
      const float bcol = bias[col];
#pragma unroll
      for (int mt = 0; mt < 4; ++mt) {
        const int row0 = bm * 128 + wm + mt * 16 + q * 4;
        u16x4 o;
#pragma unroll
        for (int r = 0; r < 4; ++r) o[r] = f2bf(acc[mt][nt][r] + bcol);
        // VT[b][col][p]: 4 consecutive p per store, same b (row0 % 4 == 0)
        *(u16x4*)&outb[((row0 >> 10) << 19) + (col << 10) + (row0 & 1023)] = o;
      }
    }
  } else {
    // swapped: row = ...+c, col = ...+q*4+r (consecutive)
#pragma unroll
    for (int mt = 0; mt < 4; ++mt) {
      const int row = bm * 128 + wm + mt * 16 + c;
#pragma unroll
      for (int nt = 0; nt < 4; ++nt) {
        const int col0 = bn * 128 + wn + nt * 16 + q * 4;
        const f32x4 bv = *(const f32x4*)&bias[col0];
        u16x4 o;
#pragma unroll
        for (int r = 0; r < 4; ++r) o[r] = f2bf((acc[mt][nt][r] + bv[r]) * scale);
        *(u16x4*)&outb[row * 512 + col0] = o;
      }
    }
  }
}

__global__ __launch_bounds__(256, 3) void k_gemm_qkv(
    const float* __restrict__ tok, const float* __restrict__ pat,
    const unsigned short* __restrict__ WT,
    const float* __restrict__ bq, const float* __restrict__ bk,
    const float* __restrict__ bv,
    unsigned short* __restrict__ QB, unsigned short* __restrict__ KB,
    unsigned short* __restrict__ VTB) {
  __shared__ unsigned short sA[2 * 128 * 32];
  __shared__ unsigned short sB[3 * 128 * 32];
  // XCD-aware bijective swizzle (768 = 8 x 96): all 4 bn-blocks of one bm
  // land on one XCD -> A panel fetched once per XCD L2, not 4x.
  const int hw = blockIdx.x;
  const int bid = (hw & 7) * 96 + (hw >> 3);
  if (bid < 512) {
    // scale = 0.125 * log2(e): scores come out in log2 domain for exp2
    gemm_qkv_body<0>(tok, WT, bq, QB, bid, sA, sB, 0.18033688011112042f);
  } else if (bid < 640) {
    gemm_qkv_body<1>(pat, WT + 262144, bk, KB, bid - 512, sA, sB, 1.0f);
  } else {
    gemm_qkv_body<2>(pat, WT + 524288, bv, VTB, bid - 640, sA, sB, 1.0f);
  }
}

// ---------------------------------------------------------------------------
// Out-projection GEMM, 128x128, 3-buffer counted-vmcnt DMA pipeline with
// swizzled LDS (pre-swizzled DMA sources + swizzled fragment reads):
// out = CTX @ Wo + bo + resid (fp32), pure f32x4 epilogue.
// ---------------------------------------------------------------------------
__global__ __launch_bounds__(256) void k_gemm_o(
    const unsigned short* __restrict__ A, const unsigned short* __restrict__ Wt,
    const float* __restrict__ bias, float* __restrict__ outf,
    const float* __restrict__ resid) {
  __shared__ unsigned short sA[3 * 128 * 32];
  __shared__ unsigned short sB[3 * 128 * 32];
  const int tid = threadIdx.x;
  const int wave = tid >> 6, lane = tid & 63;
  const int q = lane >> 4, c = lane & 15;
  // XCD-aware bijective swizzle (512 = 8 x 64)
  const int hw = blockIdx.x;
  const int obid = (hw & 7) * 64 + (hw >> 3);
  const int bm = obid >> 2, bn = obid & 3;
  const int wm = (wave >> 1) * 64, wn = (wave & 1) * 64;
  const int lr = lane >> 2;
  const int swS = (((lane & 3) - (lane >> 3)) & 3) * 8;  // DMA source group

  f32x4 acc[4][4];
#pragma unroll
  for (int i = 0; i < 4; ++i)
#pragma unroll
    for (int j = 0; j < 4; ++j) acc[i][j] = (f32x4){0.f, 0.f, 0.f, 0.f};

  const int rowA0 = bm * 128, rowB0 = bn * 128;

  auto stage = [&](int t) {
    const int kn = t * 32;
    unsigned short* dA = sA + (t % 3) * 4096;
    unsigned short* dB = sB + (t % 3) * 4096;
#pragma unroll
    for (int qq = 0; qq < 2; ++qq) {
      const int chunk = wave * 2 + qq;
      load_lds16(&A[(rowA0 + chunk * 16 + lr) * 512 + kn + swS], &dA[chunk * 512]);
      load_lds16(&Wt[(rowB0 + chunk * 16 + lr) * 512 + kn + swS], &dB[chunk * 512]);
    }
  };

  stage(0);
  stage(1);
  asm volatile("s_waitcnt vmcnt(4)" ::: "memory");
  __builtin_amdgcn_s_barrier();

#pragma unroll 1
  for (int i = 0; i < 16; ++i) {
    if (i + 2 < 16) stage(i + 2);
    const unsigned short* curA = sA + (i % 3) * 4096;
    const unsigned short* curB = sB + (i % 3) * 4096;
    bf16x8 af[4], bfr[4];
#pragma unroll
    for (int mt = 0; mt < 4; ++mt)
      af[mt] = __builtin_bit_cast(bf16x8,
          *(const u16x8*)&curA[(wm + mt * 16 + c) * 32 + sw_rd(c, q)]);
#pragma unroll
    for (int nt = 0; nt < 4; ++nt)
      bfr[nt] = __builtin_bit_cast(bf16x8,
          *(const u16x8*)&curB[(wn + nt * 16 + c) * 32 + sw_rd(c, q)]);
#pragma unroll
    for (int mt = 0; mt < 4; ++mt)
#pragma unroll
      for (int nt = 0; nt < 4; ++nt)
        acc[mt][nt] = mfma16(bfr[nt], af[mt], acc[mt][nt]);  // swapped: C^T frag
    if (i < 15) {
      if (i + 2 < 16) asm volatile("s_waitcnt vmcnt(4)" ::: "memory");
      else            asm volatile("s_waitcnt vmcnt(0)" ::: "memory");
      __builtin_amdgcn_s_barrier();
    }
  }

#pragma unroll
  for (int mt = 0; mt < 4; ++mt) {
    const int row = bm * 128 + wm + mt * 16 + c;
#pragma unroll
    for (int nt = 0; nt < 4; ++nt) {
      const int col0 = bn * 128 + wn + nt * 16 + q * 4;
      const int o = row * 512 + col0;
      const f32x4 bv = *(const f32x4*)&bias[col0];
      const f32x4 rv = *(const f32x4*)&resid[o];
      f32x4 ov;
#pragma unroll
      for (int r = 0; r < 4; ++r) ov[r] = acc[mt][nt][r] + bv[r] + rv[r];
      *(f32x4*)&outf[o] = ov;
    }
  }
}

// ---------------------------------------------------------------------------
// Kernel 3: block-causal cross attention, no-max softmax in log2 domain.
// (Unchanged; sK stride 88 and sV stride 40 are already bank-conflict-free.)
// ---------------------------------------------------------------------------
__global__ __launch_bounds__(256) void k_attn(
    const unsigned short* __restrict__ Q,   // [B*T][512], scaled by .125*log2e
    const unsigned short* __restrict__ K,   // [B*P][512]
    const unsigned short* __restrict__ VT,  // [B][512][1024]
    unsigned short* __restrict__ CTX) {     // [B*T][512]
  __shared__ unsigned short sK[2][32 * 88];
  __shared__ unsigned short sV[2][64 * 40];

  const int tid = threadIdx.x;
  const int lane = tid & 63;
  const int wave = tid >> 6;
  const int q = lane >> 4, c = lane & 15;

  const int g = blockIdx.x >> 5;               // [0,32)
  const int tg = (g < 16) ? g : 47 - g;        // uniform-per-CU mapping
  const int bh = blockIdx.x & 31;
  const int b = bh >> 3, h = bh & 7;
  const int t0 = tg * 128 + wave * 32;
  const int tA = t0 + c, tB = t0 + 16 + c;

  const int qbA = (b * TT + tA) * 512 + h * 64 + q * 8;
  const int qbB = (b * TT + tB) * 512 + h * 64 + q * 8;
  const bf16x8 qfA0 = __builtin_bit_cast(bf16x8, *(const u16x8*)&Q[qbA]);
  const bf16x8 qfA1 = __builtin_bit_cast(bf16x8, *(const u16x8*)&Q[qbA + 32]);
  const bf16x8 qfB0 = __builtin_bit_cast(bf16x8, *(const u16x8*)&Q[qbB]);
  const bf16x8 qfB1 = __builtin_bit_cast(bf16x8, *(const u16x8*)&Q[qbB + 32]);

  f32x4 oA[4], oB[4];
#pragma unroll
  for (int m = 0; m < 4; ++m) {
    oA[m] = (f32x4){0.f, 0.f, 0.f, 0.f};
    oB[m] = (f32x4){0.f, 0.f, 0.f, 0.f};
  }
  f32x4 lA = (f32x4){0.f, 0.f, 0.f, 0.f};
  f32x4 lB = lA;
  const u16x8 onesu = {0x3F80, 0x3F80, 0x3F80, 0x3F80, 0x3F80, 0x3F80, 0x3F80, 0x3F80};
  const bf16x8 ones = __builtin_bit_cast(bf16x8, onesu);

  const int ntile = tg + 1;
  const int krow = tid >> 3, kcol = (tid & 7) * 8;
  const int vrow = tid >> 2, vcol = (tid & 3) * 8;
  const int kg = (b * PP + krow) * 512 + h * 64 + kcol;
  const int vg = (b << 19) + ((h * 64 + vrow) << 10) + vcol;

  // stage tile 0
  u16x8 kreg = *(const u16x8*)&K[kg];
  u16x8 vreg = *(const u16x8*)&VT[vg];
  *(u16x8*)&sK[0][krow * 88 + kcol] = kreg;
  *(u16x8*)&sV[0][vrow * 40 + vcol] = vreg;
  __syncthreads();

#pragma unroll 1
  for (int pt = 0; pt < ntile; ++pt) {
    const int buf = pt & 1;
    const bool more = (pt + 1 < ntile);
    if (more) {  // prefetch next tile (overlaps this tile's compute)
      kreg = *(const u16x8*)&K[kg + (pt + 1) * 32 * 512];
      vreg = *(const u16x8*)&VT[vg + (pt + 1) * 32];
    }
    const unsigned short* bK = sK[buf];
    const unsigned short* bV = sV[buf];

    const bf16x8 ka0 = __builtin_bit_cast(bf16x8, *(const u16x8*)&bK[c * 88 + q * 8]);
    const bf16x8 ka1 = __builtin_bit_cast(bf16x8, *(const u16x8*)&bK[c * 88 + 32 + q * 8]);
    const bf16x8 kb0 = __builtin_bit_cast(bf16x8, *(const u16x8*)&bK[(16 + c) * 88 + q * 8]);
    const bf16x8 kb1 = __builtin_bit_cast(bf16x8, *(const u16x8*)&bK[(16 + c) * 88 + 32 + q * 8]);

    const f32x4 z = (f32x4){0.f, 0.f, 0.f, 0.f};
    __builtin_amdgcn_s_setprio(1);
    f32x4 sA0 = mfma16(ka1, qfA1, mfma16(ka0, qfA0, z));  // patches p0+q*4+r
    f32x4 sA1 = mfma16(kb1, qfA1, mfma16(kb0, qfA0, z));  // patches p0+16+q*4+r
    f32x4 sB0 = mfma16(ka1, qfB1, mfma16(ka0, qfB0, z));
    f32x4 sB1 = mfma16(kb1, qfB1, mfma16(kb0, qfB0, z));
    __builtin_amdgcn_s_setprio(0);

    if (pt + 1 == ntile) {  // only the last tile crosses the causal boundary
      const int p0 = pt * 32;
      const int limA = tA >> 2, limB = tB >> 2;
      const int pb0 = p0 + q * 4, pb1 = p0 + 16 + q * 4;
#pragma unroll
      for (int r = 0; r < 4; ++r) {
        if (pb0 + r > limA) sA0[r] = -1e30f;
        if (pb1 + r > limA) sA1[r] = -1e30f;
        if (pb0 + r > limB) sB0[r] = -1e30f;
        if (pb1 + r > limB) sB1[r] = -1e30f;
      }
    }

    float pA0[4], pA1[4], pB0[4], pB1[4];
#pragma unroll
    for (int r = 0; r < 4; ++r) {
      pA0[r] = fexp2(sA0[r]);
      pA1[r] = fexp2(sA1[r]);
      pB0[r] = fexp2(sB0[r]);
      pB1[r] = fexp2(sB1[r]);
    }

    // pack + in-register exchange (no LDS)
    const bf16x8 pbA = p_exchange(packtr(pA0[0], pA0[1]), packtr(pA0[2], pA0[3]),
                                  packtr(pA1[0], pA1[1]), packtr(pA1[2], pA1[3]), q, c);
    const bf16x8 pbB = p_exchange(packtr(pB0[0], pB0[1]), packtr(pB0[2], pB0[3]),
                                  packtr(pB1[0], pB1[1]), packtr(pB1[2], pB1[3]), q, c);

    // ctx^T += V^T . P^T ; l += ones . P^T
    __builtin_amdgcn_s_setprio(1);
#pragma unroll
    for (int mt = 0; mt < 4; ++mt) {
      const bf16x8 vf =
          __builtin_bit_cast(bf16x8, *(const u16x8*)&bV[(mt * 16 + c) * 40 + q * 8]);
      oA[mt] = mfma16(vf, pbA, oA[mt]);
      oB[mt] = mfma16(vf, pbB, oB[mt]);
    }
    lA = mfma16(ones, pbA, lA);
    lB = mfma16(ones, pbB, lB);
    __builtin_amdgcn_s_setprio(0);

    if (more) {  // write next tile into the other buffer, single barrier
      *(u16x8*)&sK[buf ^ 1][krow * 88 + kcol] = kreg;
      *(u16x8*)&sV[buf ^ 1][vrow * 40 + vcol] = vreg;
      __syncthreads();
    }
  }

  const float invA = 1.f / lA[0];
  const float invB = 1.f / lB[0];
  const int obA = (b * TT + tA) * 512 + h * 64 + q * 4;
  const int obB = (b * TT + tB) * 512 + h * 64 + q * 4;
#pragma unroll
  for (int mt = 0; mt < 4; ++mt) {
    u16x4 oa, ob;
#pragma unroll
    for (int r = 0; r < 4; ++r) {
      oa[r] = f2bf(oA[mt][r] * invA);
      ob[r] = f2bf(oB[mt][r] * invB);
    }
    *(u16x4*)&CTX[obA + mt * 16] = oa;
    *(u16x4*)&CTX[obB + mt * 16] = ob;
  }
}

// ---------------------------------------------------------------------------
extern "C" void kernel_launch(void* const* d_in, const int* in_sizes, int n_in,
                              void* d_out, int out_size, void* d_ws, size_t ws_size,
                              hipStream_t stream) {
  const float* tok = (const float*)d_in[0];
  const float* pat = (const float*)d_in[1];
  const float* Wq = (const float*)d_in[2];
  const float* Wk = (const float*)d_in[3];
  const float* Wv = (const float*)d_in[4];
  const float* bq = (const float*)d_in[5];
  const float* bk = (const float*)d_in[6];
  const float* bv = (const float*)d_in[7];
  const float* Wo = (const float*)d_in[8];
  const float* bo = (const float*)d_in[9];
  float* out = (float*)d_out;

  unsigned short* ws = (unsigned short*)d_ws;
  unsigned short* WT = ws;                   // 4 x 512 x 512
  unsigned short* QB = ws + 11534336;        // 16384 x 512
  unsigned short* KB = ws + 19922944;        // 4096 x 512
  unsigned short* VTB = ws + 22020096;       // [4][512][1024]
  unsigned short* CTX = ws + 24117248;       // 16384 x 512   (ends 65 MB)

  k_convW<<<1024, 256, 0, stream>>>(Wq, Wk, Wv, Wo, WT);
  k_gemm_qkv<<<768, 256, 0, stream>>>(tok, pat, WT, bq, bk, bv, QB, KB, VTB);
  k_attn<<<1024, 256, 0, stream>>>(QB, KB, VTB, CTX);
  k_gemm_o<<<512, 256, 0, stream>>>(CTX, WT + 786432, bo, out, tok);
}